// Round 7
// baseline (515.763 us; speedup 1.0000x reference)
//
#include <hip/hip_runtime.h>
#include <hip/hip_bf16.h>
#include <math.h>

// Problem constants
#define B_   8
#define H_   8
#define S_   2048
#define D_   64      // head dim
#define BH_  64      // B*H
#define DPROJ_ 512

typedef __attribute__((ext_vector_type(8)))  _Float16 f16x8;
typedef __attribute__((ext_vector_type(4)))  _Float16 f16x4;
typedef __attribute__((ext_vector_type(4)))  float    f32x4;
typedef __attribute__((ext_vector_type(16))) float    f32x16;
typedef __attribute__((ext_vector_type(4)))  int      i32x4;

static __device__ __forceinline__ short f16bits(float f) {
    return __builtin_bit_cast(short, (_Float16)f);   // v_cvt_f16_f32 (RNE)
}

static __device__ __forceinline__ f16x8 load8_f32_f16(const float* p) {
    const float4 a = ((const float4*)p)[0];
    const float4 b = ((const float4*)p)[1];
    f16x8 r;
    r[0] = (_Float16)a.x; r[1] = (_Float16)a.y; r[2] = (_Float16)a.z; r[3] = (_Float16)a.w;
    r[4] = (_Float16)b.x; r[5] = (_Float16)b.y; r[6] = (_Float16)b.z; r[7] = (_Float16)b.w;
    return r;
}

// ---------------------------------------------------------------------------
// Kernel 1a: Q/K projection (unchanged — passes, minor cost).
// ---------------------------------------------------------------------------
#define QKST 520

__global__ __launch_bounds__(256)
void proj_qk_kernel(const float* __restrict__ query, const float* __restrict__ key,
                    const float* __restrict__ Wq, const float* __restrict__ bq,
                    const float* __restrict__ Wk, const float* __restrict__ bk,
                    short* __restrict__ qws, short* __restrict__ kws)
{
    __shared__ __align__(16) short tile[16 * QKST];

    const int tid  = threadIdx.x;
    const int wave = tid >> 6;
    const int lane = tid & 63;
    const int n    = lane & 15;
    const int quad = lane >> 4;
    const int r0   = blockIdx.x * 16;
    const int kind = blockIdx.y;             // 0=q, 1=k
    const int b    = r0 >> 11;
    const int s0   = r0 & 2047;
    const float QS = 0.1125f;                // (1-dropout)/num_heads = 0.9/8

    const float* X    = kind ? key : query;
    const float* W    = kind ? Wk  : Wq;
    const float* bias = kind ? bk  : bq;
    short*       ows  = kind ? kws : qws;

    f16x8 af = load8_f32_f16(X + (r0 + n) * 32 + quad * 8);
    #pragma unroll
    for (int i = 0; i < 8; ++i) {
        const int c0 = wave * 128 + i * 16;
        f16x8 bfr = load8_f32_f16(W + (c0 + n) * 32 + quad * 8);
        f32x4 acc = {0.f, 0.f, 0.f, 0.f};
        acc = __builtin_amdgcn_mfma_f32_16x16x32_f16(af, bfr, acc, 0, 0, 0);
        const int c = c0 + n;
        const float bsf = bias[c];
        #pragma unroll
        for (int r = 0; r < 4; ++r) {
            float v = acc[r] + bsf;
            if (kind == 0) v *= QS;
            tile[(quad * 4 + r) * QKST + c] = f16bits(v);
        }
    }
    __syncthreads();

    #pragma unroll
    for (int k = 0; k < 4; ++k) {
        const int slot = k * 256 + tid;
        const int li   = slot & 7;
        const int chunk= slot >> 3;
        const int row  = chunk & 15;
        const int h    = chunk >> 4;
        uint4 vv = *(const uint4*)(tile + row * QKST + h * 64 + li * 8);
        *(uint4*)(ows + ((size_t)(b * 8 + h) * S_ + s0 + row) * 64 + li * 8) = vv;
    }
}

// ---------------------------------------------------------------------------
// Kernel 1b: V projection (unchanged). v_ws: [BH][64][S] f16.
// ---------------------------------------------------------------------------
__global__ __launch_bounds__(256)
void proj_v_kernel(const float* __restrict__ value,
                   const float* __restrict__ Wv, const float* __restrict__ bv,
                   short* __restrict__ vws)
{
    __shared__ __align__(16) short vtile[2 * 256 * 32];   // 32 KB

    const int tid  = threadIdx.x;
    const int wave = tid >> 6;
    const int lane = tid & 63;
    const int n    = lane & 15;
    const int quad = lane >> 4;
    const int r0   = blockIdx.x * 64;
    const int cb   = blockIdx.y * 256;
    const int b    = r0 >> 11;
    const int s0   = r0 & 2047;
    const int sub  = wave >> 1;
    const int sh   = (wave & 1) * 16;

    f16x8 bfr = load8_f32_f16(value + (r0 + sub * 32 + sh + n) * 32 + quad * 8);
    #pragma unroll
    for (int i = 0; i < 16; ++i) {
        const int c0 = cb + i * 16;
        f16x8 af = load8_f32_f16(Wv + (c0 + n) * 32 + quad * 8);
        f32x4 acc = {0.f, 0.f, 0.f, 0.f};
        acc = __builtin_amdgcn_mfma_f32_16x16x32_f16(af, bfr, acc, 0, 0, 0);
        #pragma unroll
        for (int r = 0; r < 4; ++r) {
            const int dc = c0 + quad * 4 + r;
            float v = acc[r] + bv[dc];
            vtile[(sub * 256 + (dc - cb)) * 32 + sh + n] = f16bits(v);
        }
    }
    __syncthreads();

    #pragma unroll
    for (int k = 0; k < 8; ++k) {
        const int slot = k * 256 + tid;
        const int li   = slot & 3;
        const int cl   = (slot >> 2) & 255;
        const int sb   = slot >> 10;
        const int c    = cb + cl;
        uint4 vv = *(const uint4*)(vtile + (sb * 256 + cl) * 32 + li * 8);
        *(uint4*)(vws + ((size_t)(b * 8 + (c >> 6)) * 64 + (c & 63)) * S_
                      + s0 + sb * 32 + li * 8) = vv;
    }
}

// ===========================================================================
// Flash attention body (shared by split-k partial and full variants).
// Computes per-wave O^T accumulators (2 qg x 2 d-tiles f32x16) and per-lane
// row sums pl[2] over k range [ks, ks+niter*32).
// ===========================================================================
#define OST 68   // epilogue LDS row stride (f32)

struct FlashAcc {
    f32x16 o[2][2];
    float  pl[2];
};

static __device__ __forceinline__ void flash_body(
    const short* __restrict__ qbase, const short* __restrict__ kbase,
    const short* __restrict__ vbase, int q0, int ks, int niter, FlashAcc& A,
    int m32, int lh)
{
    const int koff = lh * 8;
    const bool lh0 = (lh == 0);

    // Q^T B-frags (held): qb[qg][h]: B[d=h*16+lh*8+j][q=m32]
    f16x8 qb[2][4];
    #pragma unroll
    for (int qg = 0; qg < 2; ++qg)
        #pragma unroll
        for (int h = 0; h < 4; ++h)
            qb[qg][h] = *(const f16x8*)(qbase + (q0 + qg * 32 + m32) * D_ + h * 16 + koff);

    #pragma unroll
    for (int qg = 0; qg < 2; ++qg) {
        A.pl[qg] = 0.f;
        #pragma unroll
        for (int t = 0; t < 2; ++t)
            #pragma unroll
            for (int r = 0; r < 16; ++r) A.o[qg][t][r] = 0.f;
    }

    // K A-frags / V^T A-frags, double-buffered
    f16x8 kf[2][4], va[2][4];
    #pragma unroll
    for (int h = 0; h < 4; ++h)
        kf[0][h] = *(const f16x8*)(kbase + (size_t)(ks + m32) * D_ + h * 16 + koff);
    #pragma unroll
    for (int t = 0; t < 2; ++t)
        #pragma unroll
        for (int kh = 0; kh < 2; ++kh)
            va[0][t * 2 + kh] = *(const f16x8*)(vbase + (size_t)(t * 32 + m32) * S_ + ks + kh * 16 + koff);

    #pragma unroll 2
    for (int it = 0; it < niter; ++it) {
        const int cur = it & 1, nx = cur ^ 1;
        const int nkt = ks + ((((it + 1) & (niter - 1))) << 5);   // wrap: harmless re-read
        #pragma unroll
        for (int h = 0; h < 4; ++h)
            kf[nx][h] = *(const f16x8*)(kbase + (size_t)(nkt + m32) * D_ + h * 16 + koff);
        #pragma unroll
        for (int t = 0; t < 2; ++t)
            #pragma unroll
            for (int kh = 0; kh < 2; ++kh)
                va[nx][t * 2 + kh] = *(const f16x8*)(vbase + (size_t)(t * 32 + m32) * S_ + nkt + kh * 16 + koff);

        #pragma unroll
        for (int qg = 0; qg < 2; ++qg) {
            f32x16 st;
            #pragma unroll
            for (int r = 0; r < 16; ++r) st[r] = 0.f;
            #pragma unroll
            for (int h = 0; h < 4; ++h)
                st = __builtin_amdgcn_mfma_f32_32x32x16_f16(kf[cur][h], qb[qg][h], st, 0, 0, 0);

            float p[16];
            #pragma unroll
            for (int r = 0; r < 16; ++r) p[r] = __expf(st[r]);
            float s01 = (p[0]+p[1]) + (p[2]+p[3]);
            float s23 = (p[4]+p[5]) + (p[6]+p[7]);
            float s45 = (p[8]+p[9]) + (p[10]+p[11]);
            float s67 = (p[12]+p[13]) + (p[14]+p[15]);
            A.pl[qg] += (s01 + s23) + (s45 + s67);

            unsigned int pk[8], xk[8];
            #pragma unroll
            for (int i = 0; i < 8; ++i)
                pk[i] = __builtin_bit_cast(unsigned int,
                          __builtin_amdgcn_cvt_pkrtz(p[2 * i], p[2 * i + 1]));
            #pragma unroll
            for (int i = 0; i < 8; ++i)
                xk[i] = (unsigned int)__shfl_xor((int)pk[i], 32);

            i32x4 bi0, bi1;
            bi0[0] = (int)(lh0 ? pk[0] : xk[2]);
            bi0[1] = (int)(lh0 ? pk[1] : xk[3]);
            bi0[2] = (int)(lh0 ? xk[0] : pk[2]);
            bi0[3] = (int)(lh0 ? xk[1] : pk[3]);
            bi1[0] = (int)(lh0 ? pk[4] : xk[6]);
            bi1[1] = (int)(lh0 ? pk[5] : xk[7]);
            bi1[2] = (int)(lh0 ? xk[4] : pk[6]);
            bi1[3] = (int)(lh0 ? xk[5] : pk[7]);
            f16x8 bf0 = __builtin_bit_cast(f16x8, bi0);
            f16x8 bf1 = __builtin_bit_cast(f16x8, bi1);

            #pragma unroll
            for (int t = 0; t < 2; ++t) {
                A.o[qg][t] = __builtin_amdgcn_mfma_f32_32x32x16_f16(va[cur][t * 2 + 0], bf0, A.o[qg][t], 0, 0, 0);
                A.o[qg][t] = __builtin_amdgcn_mfma_f32_32x32x16_f16(va[cur][t * 2 + 1], bf1, A.o[qg][t], 0, 0, 0);
            }
        }
    }
}

// ---------------------------------------------------------------------------
// Kernel 2a: split-k flash partial. grid (S/256, BH, 2); each z-half covers
// 1024 k. Writes raw O^T partials (f16, [b,s,h,d] layout) + row sums (f32).
// 1024 blocks = 4 blocks/CU = 4 waves/SIMD (TLP to cover serial chains).
// ---------------------------------------------------------------------------
__global__ __launch_bounds__(256, 4)
void flash_part_kernel(const short* __restrict__ qws, const short* __restrict__ kws,
                       const short* __restrict__ vws, short* __restrict__ po,
                       float* __restrict__ lws)
{
    __shared__ __align__(16) float olds[4 * 32 * OST];

    const int tid  = threadIdx.x;
    const int wave = tid >> 6;
    const int lane = tid & 63;
    const int m32  = lane & 31;
    const int lh   = lane >> 5;
    const int bh   = blockIdx.y;
    const int kz   = blockIdx.z;
    const int q0   = blockIdx.x * 256 + wave * 64;
    const int ks   = kz << 10;

    const short* qbase = qws + (size_t)bh * S_ * D_;
    const short* kbase = kws + (size_t)bh * S_ * D_;
    const short* vbase = vws + (size_t)bh * D_ * S_;

    FlashAcc A;
    flash_body(qbase, kbase, vbase, q0, ks, 32, A, m32, lh);

    // epilogue: raw partials (no normalize) — combine kernel finishes.
    const int b = bh >> 3, h = bh & 7;
    float* ow = olds + wave * (32 * OST);
    short* pob = po + (size_t)kz * ((size_t)B_ * S_ * DPROJ_);
    #pragma unroll
    for (int qg = 0; qg < 2; ++qg) {
        float rs = A.pl[qg] + __shfl_xor(A.pl[qg], 32);
        if (lh == 0)
            lws[(size_t)kz * (BH_ * S_) + bh * S_ + q0 + qg * 32 + m32] = rs;
        #pragma unroll
        for (int t = 0; t < 2; ++t)
            #pragma unroll
            for (int g = 0; g < 4; ++g) {
                f32x4 w;
                w[0] = A.o[qg][t][g * 4 + 0];
                w[1] = A.o[qg][t][g * 4 + 1];
                w[2] = A.o[qg][t][g * 4 + 2];
                w[3] = A.o[qg][t][g * 4 + 3];
                *(f32x4*)(ow + m32 * OST + t * 32 + 8 * g + 4 * lh) = w;
            }
        #pragma unroll
        for (int c = 0; c < 8; ++c) {
            const int row = c * 4 + (lane >> 4);
            f32x4 v = *(const f32x4*)(ow + row * OST + (lane & 15) * 4);
            const int sq = q0 + qg * 32 + row;
            f16x4 hv;
            hv[0] = (_Float16)v[0]; hv[1] = (_Float16)v[1];
            hv[2] = (_Float16)v[2]; hv[3] = (_Float16)v[3];
            *(f16x4*)(pob + ((size_t)(b * S_ + sq)) * DPROJ_ + h * 64 + (lane & 15) * 4) = hv;
        }
    }
}

// ---------------------------------------------------------------------------
// Kernel 2b: combine partials: out = (O0+O1) / (l0+l1). Streaming, coalesced.
// grid: B*S*512/(256*4) = 8192 blocks.
// ---------------------------------------------------------------------------
__global__ __launch_bounds__(256)
void combine_kernel(const short* __restrict__ po, const float* __restrict__ lws,
                    float* __restrict__ out)
{
    const int i4 = (blockIdx.x * 256 + threadIdx.x) * 4;
    const int r  = i4 >> 9;          // b*S + s
    const int b  = r >> 11;
    const int s  = r & 2047;
    const int h  = (i4 >> 6) & 7;
    const int li = (b * 8 + h) * S_ + s;
    const float rl = 1.0f / (lws[li] + lws[BH_ * S_ + li]);
    const f16x4 a0 = *(const f16x4*)(po + i4);
    const f16x4 a1 = *(const f16x4*)(po + (size_t)B_ * S_ * DPROJ_ + i4);
    float4 o;
    o.x = ((float)a0[0] + (float)a1[0]) * rl;
    o.y = ((float)a0[1] + (float)a1[1]) * rl;
    o.z = ((float)a0[2] + (float)a1[2]) * rl;
    o.w = ((float)a0[3] + (float)a1[3]) * rl;
    *(float4*)(out + i4) = o;
}

// ---------------------------------------------------------------------------
// Kernel 2 (fallback): full-k flash, normalized store (R6 behavior) — used
// only if ws_size can't hold the split-k partials.
// ---------------------------------------------------------------------------
__global__ __launch_bounds__(256, 2)
void flash_full_kernel(const short* __restrict__ qws, const short* __restrict__ kws,
                       const short* __restrict__ vws, float* __restrict__ out)
{
    __shared__ __align__(16) float olds[4 * 32 * OST];

    const int tid  = threadIdx.x;
    const int wave = tid >> 6;
    const int lane = tid & 63;
    const int m32  = lane & 31;
    const int lh   = lane >> 5;
    const int bh   = blockIdx.y;
    const int q0   = blockIdx.x * 256 + wave * 64;

    const short* qbase = qws + (size_t)bh * S_ * D_;
    const short* kbase = kws + (size_t)bh * S_ * D_;
    const short* vbase = vws + (size_t)bh * D_ * S_;

    FlashAcc A;
    flash_body(qbase, kbase, vbase, q0, 0, 64, A, m32, lh);

    const int b = bh >> 3, h = bh & 7;
    float* ow = olds + wave * (32 * OST);
    #pragma unroll
    for (int qg = 0; qg < 2; ++qg) {
        float rs = A.pl[qg] + __shfl_xor(A.pl[qg], 32);
        float rl = 1.0f / rs;
        #pragma unroll
        for (int t = 0; t < 2; ++t)
            #pragma unroll
            for (int g = 0; g < 4; ++g) {
                f32x4 w;
                w[0] = A.o[qg][t][g * 4 + 0] * rl;
                w[1] = A.o[qg][t][g * 4 + 1] * rl;
                w[2] = A.o[qg][t][g * 4 + 2] * rl;
                w[3] = A.o[qg][t][g * 4 + 3] * rl;
                *(f32x4*)(ow + m32 * OST + t * 32 + 8 * g + 4 * lh) = w;
            }
        #pragma unroll
        for (int c = 0; c < 8; ++c) {
            const int row = c * 4 + (lane >> 4);
            f32x4 v = *(const f32x4*)(ow + row * OST + (lane & 15) * 4);
            const int sq = q0 + qg * 32 + row;
            *(f32x4*)(out + ((size_t)(b * S_ + sq)) * DPROJ_ + h * 64 + (lane & 15) * 4) = v;
        }
    }
}

// ---------------------------------------------------------------------------
extern "C" void kernel_launch(void* const* d_in, const int* in_sizes, int n_in,
                              void* d_out, int out_size, void* d_ws, size_t ws_size,
                              hipStream_t stream)
{
    const float* query = (const float*)d_in[0];
    const float* key   = (const float*)d_in[1];
    const float* value = (const float*)d_in[2];
    // d_in[3] = mask (int32) -- only its shape feeds the reference; unused.
    const float* Wq = (const float*)d_in[4];
    const float* bq = (const float*)d_in[5];
    const float* Wk = (const float*)d_in[6];
    const float* bk = (const float*)d_in[7];
    const float* Wv = (const float*)d_in[8];
    const float* bv = (const float*)d_in[9];

    float* out = (float*)d_out;
    short* ws  = (short*)d_ws;
    const size_t TSZ = (size_t)BH_ * S_ * D_;      // 8.4M shorts per tensor
    short* qws = ws;
    short* kws = ws + TSZ;
    short* vws = ws + 2 * TSZ;
    short* po  = ws + 3 * TSZ;                     // 2 x 8.4M f16 partial O
    float* lws = (float*)(po + 2 * TSZ);           // 2 x BH*S f32 row sums

    const size_t need = (5 * TSZ) * 2 + (size_t)2 * BH_ * S_ * 4;  // ~85 MB

    proj_qk_kernel<<<dim3((B_ * S_) / 16, 2), 256, 0, stream>>>(
        query, key, Wq, bq, Wk, bk, qws, kws);
    proj_v_kernel<<<dim3((B_ * S_) / 64, 2), 256, 0, stream>>>(
        value, Wv, bv, vws);

    if (ws_size >= need) {
        flash_part_kernel<<<dim3(S_ / 256, BH_, 2), 256, 0, stream>>>(
            qws, kws, vws, po, lws);
        combine_kernel<<<dim3((B_ * S_ * DPROJ_) / 1024), 256, 0, stream>>>(
            po, lws, out);
    } else {
        flash_full_kernel<<<dim3(S_ / 256, BH_), 256, 0, stream>>>(
            qws, kws, vws, out);
    }
}

// Round 8
// 344.803 us; speedup vs baseline: 1.4958x; 1.4958x over previous
//
#include <hip/hip_runtime.h>
#include <hip/hip_bf16.h>
#include <math.h>

// Problem constants
#define B_   8
#define H_   8
#define S_   2048
#define D_   64      // head dim
#define BH_  64      // B*H
#define DPROJ_ 512

typedef __attribute__((ext_vector_type(8)))  _Float16 f16x8;
typedef __attribute__((ext_vector_type(4)))  float    f32x4;
typedef __attribute__((ext_vector_type(16))) float    f32x16;
typedef __attribute__((ext_vector_type(4)))  int      i32x4;

static __device__ __forceinline__ short f16bits(float f) {
    return __builtin_bit_cast(short, (_Float16)f);   // v_cvt_f16_f32 (RNE)
}

static __device__ __forceinline__ f16x8 load8_f32_f16(const float* p) {
    const float4 a = ((const float4*)p)[0];
    const float4 b = ((const float4*)p)[1];
    f16x8 r;
    r[0] = (_Float16)a.x; r[1] = (_Float16)a.y; r[2] = (_Float16)a.z; r[3] = (_Float16)a.w;
    r[4] = (_Float16)b.x; r[5] = (_Float16)b.y; r[6] = (_Float16)b.z; r[7] = (_Float16)b.w;
    return r;
}

// ---------------------------------------------------------------------------
// Kernel 1a: Q/K projection (unchanged — passes, minor cost).
// ---------------------------------------------------------------------------
#define QKST 520

__global__ __launch_bounds__(256)
void proj_qk_kernel(const float* __restrict__ query, const float* __restrict__ key,
                    const float* __restrict__ Wq, const float* __restrict__ bq,
                    const float* __restrict__ Wk, const float* __restrict__ bk,
                    short* __restrict__ qws, short* __restrict__ kws)
{
    __shared__ __align__(16) short tile[16 * QKST];

    const int tid  = threadIdx.x;
    const int wave = tid >> 6;
    const int lane = tid & 63;
    const int n    = lane & 15;
    const int quad = lane >> 4;
    const int r0   = blockIdx.x * 16;
    const int kind = blockIdx.y;             // 0=q, 1=k
    const int b    = r0 >> 11;
    const int s0   = r0 & 2047;
    const float QS = 0.1125f;                // (1-dropout)/num_heads = 0.9/8

    const float* X    = kind ? key : query;
    const float* W    = kind ? Wk  : Wq;
    const float* bias = kind ? bk  : bq;
    short*       ows  = kind ? kws : qws;

    f16x8 af = load8_f32_f16(X + (r0 + n) * 32 + quad * 8);
    #pragma unroll
    for (int i = 0; i < 8; ++i) {
        const int c0 = wave * 128 + i * 16;
        f16x8 bfr = load8_f32_f16(W + (c0 + n) * 32 + quad * 8);
        f32x4 acc = {0.f, 0.f, 0.f, 0.f};
        acc = __builtin_amdgcn_mfma_f32_16x16x32_f16(af, bfr, acc, 0, 0, 0);
        const int c = c0 + n;
        const float bsf = bias[c];
        #pragma unroll
        for (int r = 0; r < 4; ++r) {
            float v = acc[r] + bsf;
            if (kind == 0) v *= QS;
            tile[(quad * 4 + r) * QKST + c] = f16bits(v);
        }
    }
    __syncthreads();

    #pragma unroll
    for (int k = 0; k < 4; ++k) {
        const int slot = k * 256 + tid;
        const int li   = slot & 7;
        const int chunk= slot >> 3;
        const int row  = chunk & 15;
        const int h    = chunk >> 4;
        uint4 vv = *(const uint4*)(tile + row * QKST + h * 64 + li * 8);
        *(uint4*)(ows + ((size_t)(b * 8 + h) * S_ + s0 + row) * 64 + li * 8) = vv;
    }
}

// ---------------------------------------------------------------------------
// Kernel 1b: V projection (unchanged). v_ws: [BH][64][S] f16.
// ---------------------------------------------------------------------------
__global__ __launch_bounds__(256)
void proj_v_kernel(const float* __restrict__ value,
                   const float* __restrict__ Wv, const float* __restrict__ bv,
                   short* __restrict__ vws)
{
    __shared__ __align__(16) short vtile[2 * 256 * 32];   // 32 KB

    const int tid  = threadIdx.x;
    const int wave = tid >> 6;
    const int lane = tid & 63;
    const int n    = lane & 15;
    const int quad = lane >> 4;
    const int r0   = blockIdx.x * 64;
    const int cb   = blockIdx.y * 256;
    const int b    = r0 >> 11;
    const int s0   = r0 & 2047;
    const int sub  = wave >> 1;
    const int sh   = (wave & 1) * 16;

    f16x8 bfr = load8_f32_f16(value + (r0 + sub * 32 + sh + n) * 32 + quad * 8);
    #pragma unroll
    for (int i = 0; i < 16; ++i) {
        const int c0 = cb + i * 16;
        f16x8 af = load8_f32_f16(Wv + (c0 + n) * 32 + quad * 8);
        f32x4 acc = {0.f, 0.f, 0.f, 0.f};
        acc = __builtin_amdgcn_mfma_f32_16x16x32_f16(af, bfr, acc, 0, 0, 0);
        #pragma unroll
        for (int r = 0; r < 4; ++r) {
            const int dc = c0 + quad * 4 + r;
            float v = acc[r] + bv[dc];
            vtile[(sub * 256 + (dc - cb)) * 32 + sh + n] = f16bits(v);
        }
    }
    __syncthreads();

    #pragma unroll
    for (int k = 0; k < 8; ++k) {
        const int slot = k * 256 + tid;
        const int li   = slot & 3;
        const int cl   = (slot >> 2) & 255;
        const int sb   = slot >> 10;
        const int c    = cb + cl;
        uint4 vv = *(const uint4*)(vtile + (sb * 256 + cl) * 32 + li * 8);
        *(uint4*)(vws + ((size_t)(b * 8 + (c >> 6)) * 64 + (c & 63)) * S_
                      + s0 + sb * 32 + li * 8) = vv;
    }
}

// ---------------------------------------------------------------------------
// Kernel 2: flash attention, 32 q-rows per wave (1 q-group) for 4 waves/SIMD.
//   S^T = K_tile . Q^T ; P^T via cvt_pkrtz + shfl_xor(32) (register-only);
//   O^T = V^T . P^T.
// Single-buffered K/V loads (registers <=128/wave incl. AGPR: no spills);
// L2 latency covered by 4-way TLP. grid (S/128, BH) = 1024 blocks = 4/CU.
// LDS only for one-time O^T->O epilogue transpose. Output FLOAT32.
// ---------------------------------------------------------------------------
#define OST 68   // epilogue LDS row stride (f32)

__global__ __launch_bounds__(256, 4)
void flash_kernel(const short* __restrict__ qws, const short* __restrict__ kws,
                  const short* __restrict__ vws, float* __restrict__ out)
{
    __shared__ __align__(16) float olds[4 * 32 * OST];   // 34.8 KB

    const int tid  = threadIdx.x;
    const int wave = tid >> 6;
    const int lane = tid & 63;
    const int m32  = lane & 31;
    const int lh   = lane >> 5;          // lane-half
    const int koff = lh * 8;
    const bool lh0 = (lh == 0);
    const int bh   = blockIdx.y;
    const int q0   = blockIdx.x * 128 + wave * 32;

    const short* qbase = qws + (size_t)bh * S_ * D_;
    const short* kbase = kws + (size_t)bh * S_ * D_;
    const short* vbase = vws + (size_t)bh * D_ * S_;

    // Q^T B-frags (held): qb[h]: B[d=h*16+lh*8+j][q=m32]
    f16x8 qb[4];
    #pragma unroll
    for (int h = 0; h < 4; ++h)
        qb[h] = *(const f16x8*)(qbase + (q0 + m32) * D_ + h * 16 + koff);

    f32x16 o[2];        // [d-tile] O^T accumulators
    float  pl = 0.f;    // per-lane row-sum partial
    #pragma unroll
    for (int t = 0; t < 2; ++t)
        #pragma unroll
        for (int r = 0; r < 16; ++r) o[t][r] = 0.f;

    for (int it = 0; it < 64; ++it) {
        const int kt = it << 5;
        // K A-frags (rows kt+m32), V^T A-frags — single-buffered
        f16x8 kf[4], va[4];
        #pragma unroll
        for (int h = 0; h < 4; ++h)
            kf[h] = *(const f16x8*)(kbase + (size_t)(kt + m32) * D_ + h * 16 + koff);
        #pragma unroll
        for (int t = 0; t < 2; ++t)
            #pragma unroll
            for (int kh = 0; kh < 2; ++kh)
                va[t * 2 + kh] = *(const f16x8*)(vbase + (size_t)(t * 32 + m32) * S_ + kt + kh * 16 + koff);

        // S^T[k][q] for this 32k x 32q tile
        f32x16 st;
        #pragma unroll
        for (int r = 0; r < 16; ++r) st[r] = 0.f;
        #pragma unroll
        for (int h = 0; h < 4; ++h)
            st = __builtin_amdgcn_mfma_f32_32x32x16_f16(kf[h], qb[h], st, 0, 0, 0);

        // exp (q pre-scaled by 0.1125); accumulate row sums (per-lane half)
        float p[16];
        #pragma unroll
        for (int r = 0; r < 16; ++r) p[r] = __expf(st[r]);
        float s01 = (p[0]+p[1]) + (p[2]+p[3]);
        float s23 = (p[4]+p[5]) + (p[6]+p[7]);
        float s45 = (p[8]+p[9]) + (p[10]+p[11]);
        float s67 = (p[12]+p[13]) + (p[14]+p[15]);
        pl += (s01 + s23) + (s45 + s67);

        // pack pairs to f16x2 (RTZ), build PV B-frags via xor-32 swap
        unsigned int pk[8], xk[8];
        #pragma unroll
        for (int i = 0; i < 8; ++i)
            pk[i] = __builtin_bit_cast(unsigned int,
                      __builtin_amdgcn_cvt_pkrtz(p[2 * i], p[2 * i + 1]));
        #pragma unroll
        for (int i = 0; i < 8; ++i)
            xk[i] = (unsigned int)__shfl_xor((int)pk[i], 32);

        i32x4 bi0, bi1;
        bi0[0] = (int)(lh0 ? pk[0] : xk[2]);
        bi0[1] = (int)(lh0 ? pk[1] : xk[3]);
        bi0[2] = (int)(lh0 ? xk[0] : pk[2]);
        bi0[3] = (int)(lh0 ? xk[1] : pk[3]);
        bi1[0] = (int)(lh0 ? pk[4] : xk[6]);
        bi1[1] = (int)(lh0 ? pk[5] : xk[7]);
        bi1[2] = (int)(lh0 ? xk[4] : pk[6]);
        bi1[3] = (int)(lh0 ? xk[5] : pk[7]);
        f16x8 bf0 = __builtin_bit_cast(f16x8, bi0);
        f16x8 bf1 = __builtin_bit_cast(f16x8, bi1);

        // O^T[d][q] += V^T . P^T   (two d-tiles, two k-halves)
        #pragma unroll
        for (int t = 0; t < 2; ++t) {
            o[t] = __builtin_amdgcn_mfma_f32_32x32x16_f16(va[t * 2 + 0], bf0, o[t], 0, 0, 0);
            o[t] = __builtin_amdgcn_mfma_f32_32x32x16_f16(va[t * 2 + 1], bf1, o[t], 0, 0, 0);
        }
    }

    // epilogue: complete row sums across lane-halves, normalize,
    // transpose O^T -> O through per-wave LDS, coalesced f32x4 stores.
    const int b = bh >> 3, h = bh & 7;
    float* ow = olds + wave * (32 * OST);
    float rs = pl + __shfl_xor(pl, 32);
    float rl = 1.0f / rs;
    #pragma unroll
    for (int t = 0; t < 2; ++t)
        #pragma unroll
        for (int g = 0; g < 4; ++g) {
            f32x4 w;
            w[0] = o[t][g * 4 + 0] * rl;
            w[1] = o[t][g * 4 + 1] * rl;
            w[2] = o[t][g * 4 + 2] * rl;
            w[3] = o[t][g * 4 + 3] * rl;
            *(f32x4*)(ow + m32 * OST + t * 32 + 8 * g + 4 * lh) = w;
        }
    #pragma unroll
    for (int c = 0; c < 8; ++c) {
        const int row = c * 4 + (lane >> 4);
        f32x4 v = *(const f32x4*)(ow + row * OST + (lane & 15) * 4);
        const int sq = q0 + row;
        *(f32x4*)(out + ((size_t)(b * S_ + sq)) * DPROJ_ + h * 64 + (lane & 15) * 4) = v;
    }
}

// ---------------------------------------------------------------------------
extern "C" void kernel_launch(void* const* d_in, const int* in_sizes, int n_in,
                              void* d_out, int out_size, void* d_ws, size_t ws_size,
                              hipStream_t stream)
{
    const float* query = (const float*)d_in[0];
    const float* key   = (const float*)d_in[1];
    const float* value = (const float*)d_in[2];
    // d_in[3] = mask (int32) -- only its shape feeds the reference; unused.
    const float* Wq = (const float*)d_in[4];
    const float* bq = (const float*)d_in[5];
    const float* Wk = (const float*)d_in[6];
    const float* bk = (const float*)d_in[7];
    const float* Wv = (const float*)d_in[8];
    const float* bv = (const float*)d_in[9];

    float* out = (float*)d_out;
    short* ws  = (short*)d_ws;
    const size_t TSZ = (size_t)BH_ * S_ * D_;
    short* qws = ws;
    short* kws = ws + TSZ;
    short* vws = ws + 2 * TSZ;

    proj_qk_kernel<<<dim3((B_ * S_) / 16, 2), 256, 0, stream>>>(
        query, key, Wq, bq, Wk, bk, qws, kws);
    proj_v_kernel<<<dim3((B_ * S_) / 64, 2), 256, 0, stream>>>(
        value, Wv, bv, vws);
    flash_kernel<<<dim3(S_ / 128, BH_), 256, 0, stream>>>(qws, kws, vws, out);
}